// Round 6
// baseline (147.515 us; speedup 1.0000x reference)
//
#include <hip/hip_runtime.h>

#define NN 64
#define CC 128
#define TT 2048
#define SS 9
#define PAD 4
#define EPSF 1e-5f
#define TL 32                 // t columns per block
#define ROWS (CC + 2 * PAD)   // 136 staged rows
#define STRIDE 36             // 16B-aligned rows -> all-b128 LDS; 36%32=4 keeps
                              // every access pattern uniform 8-words/bank
#define NB 16                 // stat buckets

// ---------------------------------------------------------------------------
// R6: all-b128 LDS. The conv's 144 ds_read_b32/thread (~835 cyc/wave at
// 5.8 cyc) was the dominant controllable cost (~25 us/kernel-pair). With
// STRIDE=36 every LDS touch is 16B-aligned: staging writes 1x b128 (was 4x
// b32), conv reads 36x b128 (was 144x b32), transpose writes 4x b128 (was
// 16x b32), store reads 4x b128. Bank-uniform for all four patterns.
// Structure (two-kernel recompute, verified R4/R5) unchanged.
// ---------------------------------------------------------------------------
__device__ __forceinline__ void stage_tile(
    const float* __restrict__ xn, float* __restrict__ ls,
    const int t0, const int tid)
{
    const bool interior = (t0 != 0) && (t0 != TT - TL);   // block-uniform
#pragma unroll
    for (int p = 0; p < 5; ++p) {         // 136 rows x 8 lanes = 1088 slots
        const int f = tid + 256 * p;
        const int r = f >> 3;
        if (r < ROWS) {
            const int j0 = (f & 7) * 4;
            const int c2 = r - PAD;
            float4 v = make_float4(0.f, 0.f, 0.f, 0.f);
            if (c2 >= 0 && c2 < CC) {
                const int sh = c2 % SS - PAD;
                const int t  = t0 + j0 - sh;              // 4B-aligned
                const float* __restrict__ row = xn + (size_t)c2 * TT;
                if (interior) {
                    __builtin_memcpy(&v, row + t, sizeof(float4));
                } else {
                    v.x = (t     >= 0 && t     < TT) ? row[t]     : 0.f;
                    v.y = (t + 1 >= 0 && t + 1 < TT) ? row[t + 1] : 0.f;
                    v.z = (t + 2 >= 0 && t + 2 < TT) ? row[t + 2] : 0.f;
                    v.w = (t + 3 >= 0 && t + 3 < TT) ? row[t + 3] : 0.f;
                }
            }
            // 16B-aligned: (r*36 + j0)*4 bytes, j0 multiple of 4
            *reinterpret_cast<float4*>(&ls[r * STRIDE + j0]) = v;
        }
    }
}

// K1: stage -> conv (b128 reads) -> stats atomics only.
__global__ __launch_bounds__(256, 8) void conv_stats(
    const float* __restrict__ x, const float* __restrict__ cw,
    float* __restrict__ buckets)
{
    __shared__ float ls[ROWS * STRIDE];   // 19584 B -> 8 blocks/CU

    const int n   = blockIdx.y;
    const int t0  = blockIdx.x * TL;
    const int tid = threadIdx.x;
    const float* __restrict__ xn = x + (size_t)n * CC * TT;

    stage_tile(xn, ls, t0, tid);

    const int c  = tid & (CC - 1);        // fixed output channel per thread
    const int jb = (tid >> 7) * (TL / 2); // 0 or 16
    float wv[SS];
#pragma unroll
    for (int s = 0; s < SS; ++s) wv[s] = cw[c * SS + s];

    __syncthreads();

    // conv: rows c..c+8, 4x float4 per tap (16B-aligned, bank-uniform)
    const int base = c * STRIDE + jb;
    float res[TL / 2];
#pragma unroll
    for (int j = 0; j < TL / 2; ++j) res[j] = 0.f;
#pragma unroll
    for (int s = 0; s < SS; ++s) {
        const float4* rp = reinterpret_cast<const float4*>(&ls[base + s * STRIDE]);
        float4 r0 = rp[0], r1 = rp[1], r2 = rp[2], r3 = rp[3];
        const float w = wv[s];
        res[0]  = fmaf(w, r0.x, res[0]);  res[1]  = fmaf(w, r0.y, res[1]);
        res[2]  = fmaf(w, r0.z, res[2]);  res[3]  = fmaf(w, r0.w, res[3]);
        res[4]  = fmaf(w, r1.x, res[4]);  res[5]  = fmaf(w, r1.y, res[5]);
        res[6]  = fmaf(w, r1.z, res[6]);  res[7]  = fmaf(w, r1.w, res[7]);
        res[8]  = fmaf(w, r2.x, res[8]);  res[9]  = fmaf(w, r2.y, res[9]);
        res[10] = fmaf(w, r2.z, res[10]); res[11] = fmaf(w, r2.w, res[11]);
        res[12] = fmaf(w, r3.x, res[12]); res[13] = fmaf(w, r3.y, res[13]);
        res[14] = fmaf(w, r3.z, res[14]); res[15] = fmaf(w, r3.w, res[15]);
    }
    float s1 = 0.f, s2 = 0.f;
#pragma unroll
    for (int j = 0; j < TL / 2; ++j) {
        s1 += res[j];
        s2 = fmaf(res[j], res[j], s2);
    }

    // pair-combine partials through ls (reused; conv reads done after barrier)
    __syncthreads();
    ls[tid]       = s1;
    ls[256 + tid] = s2;
    __syncthreads();
    if (tid < CC) {
        float* bs = buckets + ((blockIdx.x + blockIdx.y) & (NB - 1)) * 2 * CC;
        atomicAdd(&bs[tid],      ls[tid]       + ls[tid + 128]);
        atomicAdd(&bs[CC + tid], ls[256 + tid] + ls[256 + tid + 128]);
    }
}

// K2: re-stage (L3-resident) -> conv -> fold -> norm -> transpose -> store.
__global__ __launch_bounds__(256, 8) void conv_norm_store(
    const float* __restrict__ x, const float* __restrict__ cw,
    const float* __restrict__ buckets, const float* __restrict__ gamma,
    const float* __restrict__ beta, float* __restrict__ out)
{
    __shared__ float ls[ROWS * STRIDE];   // 19584 B -> 8 blocks/CU

    const int n   = blockIdx.y;
    const int t0  = blockIdx.x * TL;
    const int tid = threadIdx.x;
    const float* __restrict__ xn = x + (size_t)n * CC * TT;

    const int c  = tid & (CC - 1);
    const int jb = (tid >> 7) * (TL / 2);

    // fold 16 buckets (L2-resident 16 KB, coalesced) -> per-thread g,b
    float t1 = 0.f, t2 = 0.f;
#pragma unroll
    for (int k = 0; k < NB; ++k) {
        t1 += buckets[k * 2 * CC + c];
        t2 += buckets[k * 2 * CC + CC + c];
    }
    const float inv_cnt = 1.0f / (float)(NN * TT);
    const float mean = t1 * inv_cnt;
    const float var  = t2 * inv_cnt - mean * mean;
    const float inv  = rsqrtf(var + EPSF);
    const float g = gamma[c] * inv;
    const float b = beta[c] - mean * g;

    float wv[SS];
#pragma unroll
    for (int s = 0; s < SS; ++s) wv[s] = cw[c * SS + s];

    stage_tile(xn, ls, t0, tid);
    __syncthreads();

    // conv (identical tap order/values to K1)
    const int base = c * STRIDE + jb;
    float res[TL / 2];
#pragma unroll
    for (int j = 0; j < TL / 2; ++j) res[j] = 0.f;
#pragma unroll
    for (int s = 0; s < SS; ++s) {
        const float4* rp = reinterpret_cast<const float4*>(&ls[base + s * STRIDE]);
        float4 r0 = rp[0], r1 = rp[1], r2 = rp[2], r3 = rp[3];
        const float w = wv[s];
        res[0]  = fmaf(w, r0.x, res[0]);  res[1]  = fmaf(w, r0.y, res[1]);
        res[2]  = fmaf(w, r0.z, res[2]);  res[3]  = fmaf(w, r0.w, res[3]);
        res[4]  = fmaf(w, r1.x, res[4]);  res[5]  = fmaf(w, r1.y, res[5]);
        res[6]  = fmaf(w, r1.z, res[6]);  res[7]  = fmaf(w, r1.w, res[7]);
        res[8]  = fmaf(w, r2.x, res[8]);  res[9]  = fmaf(w, r2.y, res[9]);
        res[10] = fmaf(w, r2.z, res[10]); res[11] = fmaf(w, r2.w, res[11]);
        res[12] = fmaf(w, r3.x, res[12]); res[13] = fmaf(w, r3.y, res[13]);
        res[14] = fmaf(w, r3.z, res[14]); res[15] = fmaf(w, r3.w, res[15]);
    }
    __syncthreads();                      // conv reads done; ls reusable

    // normalize + ReLU -> LDS transpose, b128 writes (4 floats per write)
#pragma unroll
    for (int q = 0; q < 4; ++q) {
        float4 v;
        v.x = fmaf(res[4 * q],     g, b);
        v.y = fmaf(res[4 * q + 1], g, b);
        v.z = fmaf(res[4 * q + 2], g, b);
        v.w = fmaf(res[4 * q + 3], g, b);
        v.x = v.x > 0.f ? v.x : 0.f;
        v.y = v.y > 0.f ? v.y : 0.f;
        v.z = v.z > 0.f ? v.z : 0.f;
        v.w = v.w > 0.f ? v.w : 0.f;
        *reinterpret_cast<float4*>(&ls[c * STRIDE + jb + 4 * q]) = v;
    }
    __syncthreads();

    // coalesced float4 store: 1024 float4 = 128 rows x 8 (b128 LDS reads)
    float* __restrict__ on = out + (size_t)n * CC * TT + t0;
#pragma unroll
    for (int k = 0; k < 4; ++k) {
        const int f   = tid + 256 * k;
        const int row = f >> 3;
        const int q   = (f & 7) * 4;      // 16B-aligned both sides
        const float4 v = *reinterpret_cast<const float4*>(&ls[row * STRIDE + q]);
        *reinterpret_cast<float4*>(on + (size_t)row * TT + q) = v;
    }
}

extern "C" void kernel_launch(void* const* d_in, const int* in_sizes, int n_in,
                              void* d_out, int out_size, void* d_ws, size_t ws_size,
                              hipStream_t stream)
{
    const float* x     = (const float*)d_in[0];
    const float* cw    = (const float*)d_in[1];
    const float* gamma = (const float*)d_in[2];
    const float* beta  = (const float*)d_in[3];
    float* out     = (float*)d_out;
    float* buckets = (float*)d_ws;        // [NB][2][CC] = 16 KB

    hipMemsetAsync(buckets, 0, (size_t)NB * 2 * CC * sizeof(float), stream);

    dim3 grid(TT / TL, NN);               // 64 x 64 = 4096 blocks
    conv_stats<<<grid, 256, 0, stream>>>(x, cw, buckets);
    conv_norm_store<<<grid, 256, 0, stream>>>(x, cw, buckets, gamma, beta, out);
}

// Round 7
// 141.692 us; speedup vs baseline: 1.0411x; 1.0411x over previous
//
#include <hip/hip_runtime.h>

#define NN 64
#define CC 128
#define TT 2048
#define SS 9
#define PAD 4
#define EPSF 1e-5f
#define TL 32                 // t columns per tile
#define TPB 64                // two tiles per block, software-pipelined (T14)
#define ROWS (CC + 2 * PAD)   // 136 staged rows
#define STRIDE 36             // 16B-aligned rows; bank-uniform (36%32=4)
#define NB 16                 // stat buckets

// ---------------------------------------------------------------------------
// R7: T14 async-stage split. 2 tiles/block; tile-B global loads issued into
// registers BEFORE conv-A consumes LDS, hiding HBM/L3 latency under compute.
// Halves per-block fixed cost (weight loads, bucket fold, atomic rounds).
// __launch_bounds__(256,4): ~80 VGPR (va+vb prefetch live) — no spill risk
// (R1 lesson); 4 blocks/CU, ILP replaces TLP. Arithmetic identical to R6.
// ---------------------------------------------------------------------------
__device__ __forceinline__ void tile_load(
    const float* __restrict__ xn, const int tb, const int tid,
    const bool interior, float4 (&v)[5])
{
#pragma unroll
    for (int p = 0; p < 5; ++p) {         // 136 rows x 8 lanes = 1088 slots
        const int f = tid + 256 * p;
        const int r = f >> 3;
        v[p] = make_float4(0.f, 0.f, 0.f, 0.f);
        if (r < ROWS) {
            const int c2 = r - PAD;
            if (c2 >= 0 && c2 < CC) {
                const int j0 = (f & 7) * 4;
                const int sh = c2 % SS - PAD;
                const int t  = tb + j0 - sh;              // 4B-aligned
                const float* __restrict__ row = xn + (size_t)c2 * TT;
                if (interior) {
                    __builtin_memcpy(&v[p], row + t, sizeof(float4));
                } else {
                    v[p].x = (t     >= 0 && t     < TT) ? row[t]     : 0.f;
                    v[p].y = (t + 1 >= 0 && t + 1 < TT) ? row[t + 1] : 0.f;
                    v[p].z = (t + 2 >= 0 && t + 2 < TT) ? row[t + 2] : 0.f;
                    v[p].w = (t + 3 >= 0 && t + 3 < TT) ? row[t + 3] : 0.f;
                }
            }
        }
    }
}

__device__ __forceinline__ void tile_write(
    float* __restrict__ ls, const int tid, const float4 (&v)[5])
{
#pragma unroll
    for (int p = 0; p < 5; ++p) {
        const int f = tid + 256 * p;
        const int r = f >> 3;
        if (r < ROWS)
            *reinterpret_cast<float4*>(&ls[r * STRIDE + (f & 7) * 4]) = v[p];
    }
}

__device__ __forceinline__ void conv_tile(
    const float* __restrict__ ls, const int base, const float (&wv)[SS],
    float (&res)[16])
{
#pragma unroll
    for (int j = 0; j < 16; ++j) res[j] = 0.f;
#pragma unroll
    for (int s = 0; s < SS; ++s) {
        const float4* rp = reinterpret_cast<const float4*>(&ls[base + s * STRIDE]);
        float4 r0 = rp[0], r1 = rp[1], r2 = rp[2], r3 = rp[3];
        const float w = wv[s];
        res[0]  = fmaf(w, r0.x, res[0]);  res[1]  = fmaf(w, r0.y, res[1]);
        res[2]  = fmaf(w, r0.z, res[2]);  res[3]  = fmaf(w, r0.w, res[3]);
        res[4]  = fmaf(w, r1.x, res[4]);  res[5]  = fmaf(w, r1.y, res[5]);
        res[6]  = fmaf(w, r1.z, res[6]);  res[7]  = fmaf(w, r1.w, res[7]);
        res[8]  = fmaf(w, r2.x, res[8]);  res[9]  = fmaf(w, r2.y, res[9]);
        res[10] = fmaf(w, r2.z, res[10]); res[11] = fmaf(w, r2.w, res[11]);
        res[12] = fmaf(w, r3.x, res[12]); res[13] = fmaf(w, r3.y, res[13]);
        res[14] = fmaf(w, r3.z, res[14]); res[15] = fmaf(w, r3.w, res[15]);
    }
}

// K1: pipelined 2-tile conv -> stats atomics only (one atomic round / block).
__global__ __launch_bounds__(256, 4) void conv_stats(
    const float* __restrict__ x, const float* __restrict__ cw,
    float* __restrict__ buckets)
{
    __shared__ float ls[ROWS * STRIDE];   // 19584 B

    const int n   = blockIdx.y;
    const int tA  = blockIdx.x * TPB;
    const int tB  = tA + TL;
    const int tid = threadIdx.x;
    const float* __restrict__ xn = x + (size_t)n * CC * TT;

    float4 va[5];
    tile_load(xn, tA, tid, blockIdx.x != 0, va);
    tile_write(ls, tid, va);

    const int c  = tid & (CC - 1);
    const int jb = (tid >> 7) * (TL / 2);
    float wv[SS];
#pragma unroll
    for (int s = 0; s < SS; ++s) wv[s] = cw[c * SS + s];

    __syncthreads();                      // tile A staged

    float4 vb[5];                         // B loads in flight under conv A
    tile_load(xn, tB, tid, (int)blockIdx.x != (int)gridDim.x - 1, vb);

    const int base = c * STRIDE + jb;
    float res[16];
    conv_tile(ls, base, wv, res);
    float s1 = 0.f, s2 = 0.f;
#pragma unroll
    for (int j = 0; j < 16; ++j) { s1 += res[j]; s2 = fmaf(res[j], res[j], s2); }

    __syncthreads();                      // conv A reads done
    tile_write(ls, tid, vb);
    __syncthreads();                      // tile B staged

    conv_tile(ls, base, wv, res);
#pragma unroll
    for (int j = 0; j < 16; ++j) { s1 += res[j]; s2 = fmaf(res[j], res[j], s2); }

    __syncthreads();                      // conv B reads done; ls reusable
    ls[tid]       = s1;
    ls[256 + tid] = s2;
    __syncthreads();
    if (tid < CC) {
        float* bs = buckets + ((blockIdx.x + blockIdx.y) & (NB - 1)) * 2 * CC;
        atomicAdd(&bs[tid],      ls[tid]       + ls[tid + 128]);
        atomicAdd(&bs[CC + tid], ls[256 + tid] + ls[256 + tid + 128]);
    }
}

// K2: pipelined 2-tile recompute -> fold -> normalize -> transpose -> store.
__global__ __launch_bounds__(256, 4) void conv_norm_store(
    const float* __restrict__ x, const float* __restrict__ cw,
    const float* __restrict__ buckets, const float* __restrict__ gamma,
    const float* __restrict__ beta, float* __restrict__ out)
{
    __shared__ float ls[ROWS * STRIDE];   // 19584 B

    const int n   = blockIdx.y;
    const int tA  = blockIdx.x * TPB;
    const int tB  = tA + TL;
    const int tid = threadIdx.x;
    const float* __restrict__ xn = x + (size_t)n * CC * TT;

    const int c  = tid & (CC - 1);
    const int jb = (tid >> 7) * (TL / 2);

    // fold 16 buckets (L2-resident, coalesced) -> per-thread g,b
    float t1 = 0.f, t2 = 0.f;
#pragma unroll
    for (int k = 0; k < NB; ++k) {
        t1 += buckets[k * 2 * CC + c];
        t2 += buckets[k * 2 * CC + CC + c];
    }
    const float inv_cnt = 1.0f / (float)(NN * TT);
    const float mean = t1 * inv_cnt;
    const float var  = t2 * inv_cnt - mean * mean;
    const float inv  = rsqrtf(var + EPSF);
    const float g = gamma[c] * inv;
    const float b = beta[c] - mean * g;

    float4 va[5];
    tile_load(xn, tA, tid, blockIdx.x != 0, va);
    tile_write(ls, tid, va);

    float wv[SS];
#pragma unroll
    for (int s = 0; s < SS; ++s) wv[s] = cw[c * SS + s];

    __syncthreads();                      // tile A staged

    float4 vb[5];                         // B loads hide under conv+store A
    tile_load(xn, tB, tid, (int)blockIdx.x != (int)gridDim.x - 1, vb);

    const int base = c * STRIDE + jb;
    float res[16];

#pragma unroll
    for (int half = 0; half < 2; ++half) {
        conv_tile(ls, base, wv, res);
        __syncthreads();                  // conv reads done; ls reusable

        // normalize + ReLU -> LDS transpose (b128 writes)
#pragma unroll
        for (int q = 0; q < 4; ++q) {
            float4 v;
            v.x = fmaf(res[4 * q],     g, b);
            v.y = fmaf(res[4 * q + 1], g, b);
            v.z = fmaf(res[4 * q + 2], g, b);
            v.w = fmaf(res[4 * q + 3], g, b);
            v.x = v.x > 0.f ? v.x : 0.f;
            v.y = v.y > 0.f ? v.y : 0.f;
            v.z = v.z > 0.f ? v.z : 0.f;
            v.w = v.w > 0.f ? v.w : 0.f;
            *reinterpret_cast<float4*>(&ls[c * STRIDE + jb + 4 * q]) = v;
        }
        __syncthreads();

        // coalesced float4 store: 1024 float4 = 128 rows x 8
        float* __restrict__ on = out + (size_t)n * CC * TT
                               + (half == 0 ? tA : tB);
#pragma unroll
        for (int k = 0; k < 4; ++k) {
            const int f   = tid + 256 * k;
            const int row = f >> 3;
            const int q   = (f & 7) * 4;
            const float4 v =
                *reinterpret_cast<const float4*>(&ls[row * STRIDE + q]);
            *reinterpret_cast<float4*>(on + (size_t)row * TT + q) = v;
        }

        if (half == 0) {
            __syncthreads();              // store-A reads done; ls reusable
            tile_write(ls, tid, vb);
            __syncthreads();              // tile B staged
        }
    }
}

extern "C" void kernel_launch(void* const* d_in, const int* in_sizes, int n_in,
                              void* d_out, int out_size, void* d_ws, size_t ws_size,
                              hipStream_t stream)
{
    const float* x     = (const float*)d_in[0];
    const float* cw    = (const float*)d_in[1];
    const float* gamma = (const float*)d_in[2];
    const float* beta  = (const float*)d_in[3];
    float* out     = (float*)d_out;
    float* buckets = (float*)d_ws;        // [NB][2][CC] = 16 KB

    hipMemsetAsync(buckets, 0, (size_t)NB * 2 * CC * sizeof(float), stream);

    dim3 grid(TT / TPB, NN);              // 32 x 64 = 2048 blocks
    conv_stats<<<grid, 256, 0, stream>>>(x, cw, buckets);
    conv_norm_store<<<grid, 256, 0, stream>>>(x, cw, buckets, gamma, beta, out);
}